// Round 1
// baseline (506.634 us; speedup 1.0000x reference)
//
#include <hip/hip_runtime.h>
#include <math.h>

#define THREADS 512
#define E_TILE  64
#define NBASIS  512
#define NBF     128
#define SBD     16
#define MBD     9
#define CD      128
#define BRD     5
#define NTAP    17

// LDS strides (floats, odd to soften bank conflicts)
#define XE1_S  65    // xe1_t [128 ch][65]  (channel-major, edge fast)
#define XE2_S  129   // xe2_r [64 e][129]   (edge-major, channel fast)
#define WE_S   129   // W_edge chunk [64 k][129]
#define WG1_S  33    // W_g1 [128 k][33]
#define WG2_S  129   // W_g2 chunk [32 q][129]
#define HT_S   65    // h_t [32 q][65]

// LDS offsets (floats)
#define OFF_XS   0        // 64*16
#define OFF_SH   1024     // 64*16
#define OFF_G    2048     // 64*17
#define OFF_TPA  3136     // 64*16
#define OFF_TPM  4160     // 64*9
#define OFF_SUM  4736     // 64
#define OFF_JLO  4800     // 64 (int)
#define OFF_SRC  4864     // 64 (int)
#define OFF_TGT  4928     // 64 (int)
#define OFF_XE1  4992     // 128*65 = 8320
#define OFF_XE2  13312    // 64*129 = 8256
#define OFF_W    21568    // 8320 (reused: W_edge chunks / W_g1 / W_g2 chunks)
#define OFF_H    29888    // 32*65 = 2080
#define SMEM_FLOATS 31968 // ~125 KB

__device__ __forceinline__ float fsigmoid(float x){ return 1.0f/(1.0f + __expf(-x)); }
__device__ __forceinline__ float fsilu(float x){ return x/(1.0f + __expf(-x)); }

__global__ __launch_bounds__(THREADS, 2)
void edge_block_kernel(
    const float* __restrict__ edge_distance,
    const int*   __restrict__ source_element,
    const int*   __restrict__ target_element,
    const float* __restrict__ x_sph,
    const float* __restrict__ edge_sh,
    const float* __restrict__ W_dist,
    const float* __restrict__ b_dist,
    const float* __restrict__ src_emb,
    const float* __restrict__ tgt_emb,
    const float* __restrict__ W_edge,
    const float* __restrict__ b_edge,
    const float* __restrict__ W_g1,
    const float* __restrict__ b_g1,
    const float* __restrict__ W_g2,
    const float* __restrict__ b_g2,
    const float* __restrict__ cg_mid,
    const float* __restrict__ cg_all,
    const float* __restrict__ W_path,
    float* __restrict__ out,
    int E)
{
  __shared__ float sm[SMEM_FLOATS];
  float* xs_s  = sm + OFF_XS;
  float* sh_s  = sm + OFF_SH;
  float* g_s   = sm + OFF_G;
  float* tpa_s = sm + OFF_TPA;
  float* tpm_s = sm + OFF_TPM;
  float* sum_s = sm + OFF_SUM;
  int*   jlo_s = (int*)(sm + OFF_JLO);
  int*   src_s = (int*)(sm + OFF_SRC);
  int*   tgt_s = (int*)(sm + OFF_TGT);
  float* xe1_t = sm + OFF_XE1;
  float* xe2_r = sm + OFF_XE2;
  float* W_sm  = sm + OFF_W;
  float* h_t   = sm + OFF_H;

  const int tid = threadIdx.x;
  const int eb  = blockIdx.x * E_TILE;
  const int ne  = min(E_TILE, E - eb);
  const int er  = tid >> 5;        // 0..15
  const int cq  = tid & 31;        // 0..31
  const int e0  = er << 2;         // edge tile base (4 edges)
  const int c0  = cq << 2;         // channel tile base (4 channels)

  // ---------------- P0: stage per-edge inputs + Gaussian taps ----------
  for (int idx = tid; idx < E_TILE*SBD; idx += THREADS) {
    int e = idx >> 4;
    bool v = (e < ne);
    int gidx = (eb + e)*SBD + (idx & 15);
    xs_s[idx] = v ? x_sph[gidx]   : 0.0f;
    sh_s[idx] = v ? edge_sh[gidx] : 0.0f;
  }
  if (tid < E_TILE) {
    bool v = (tid < ne);
    int ge = eb + tid;
    src_s[tid] = v ? source_element[ge] : 0;
    tgt_s[tid] = v ? target_element[ge] : 0;
  }
  const float INVD = (float)(NBASIS - 1) / 6.0f;   // 511/6
  for (int idx = tid; idx < E_TILE*NTAP; idx += THREADS) {
    int e = idx / NTAP;
    int t = idx - e*NTAP;
    bool v = (e < ne);
    float d  = v ? edge_distance[eb + e] : 0.0f;
    float jd = d * INVD;                 // position in bin units
    int jlo  = (int)floorf(jd) - 8;
    int j    = jlo + t;
    float dj = jd - (float)j;
    float g  = (v && j >= 0 && j < NBASIS) ? __expf(-0.5f*dj*dj) : 0.0f;
    g_s[e*NTAP + t] = g;
    if (t == 0) jlo_s[e] = jlo;
  }
  __syncthreads();

  // ---------------- P1: x_dist(17 taps) + emb + silu -> xe1_t[c][e] ----
  {
    float acc[4][4];
    const float4 bd = *(const float4*)(b_dist + c0);
    #pragma unroll
    for (int i=0;i<4;i++){ acc[i][0]=bd.x; acc[i][1]=bd.y; acc[i][2]=bd.z; acc[i][3]=bd.w; }
    for (int t=0; t<NTAP; t++){
      #pragma unroll
      for (int i=0;i<4;i++){
        int e = e0 + i;
        float g = g_s[e*NTAP + t];
        int j = jlo_s[e] + t;
        j = max(0, min(NBASIS-1, j));
        const float4 w = *(const float4*)(W_dist + j*NBF + c0);
        acc[i][0] += g*w.x; acc[i][1] += g*w.y; acc[i][2] += g*w.z; acc[i][3] += g*w.w;
      }
    }
    #pragma unroll
    for (int i=0;i<4;i++){
      int e = e0 + i;
      const float4 se = *(const float4*)(src_emb + src_s[e]*NBF + c0);
      const float4 te = *(const float4*)(tgt_emb + tgt_s[e]*NBF + c0);
      float v0 = fsilu(acc[i][0] + se.x + te.x);
      float v1 = fsilu(acc[i][1] + se.y + te.y);
      float v2 = fsilu(acc[i][2] + se.z + te.z);
      float v3 = fsilu(acc[i][3] + se.w + te.w);
      xe1_t[(c0+0)*XE1_S + e] = v0;
      xe1_t[(c0+1)*XE1_S + e] = v1;
      xe1_t[(c0+2)*XE1_S + e] = v2;
      xe1_t[(c0+3)*XE1_S + e] = v3;
    }
  }
  __syncthreads();

  // ---------------- P2: xe2 = silu(xe1 @ W_edge + b_edge) --------------
  {
    float acc[4][4];
    const float4 be = *(const float4*)(b_edge + c0);
    #pragma unroll
    for (int i=0;i<4;i++){ acc[i][0]=be.x; acc[i][1]=be.y; acc[i][2]=be.z; acc[i][3]=be.w; }
    for (int k0 = 0; k0 < NBF; k0 += 64) {
      if (k0 > 0) __syncthreads();
      for (int idx = tid; idx < 64*NBF; idx += THREADS) {
        int k = idx >> 7, c = idx & 127;
        W_sm[k*WE_S + c] = W_edge[(k0+k)*NBF + c];
      }
      __syncthreads();
      for (int k=0;k<64;k++){
        float a0 = xe1_t[(k0+k)*XE1_S + e0 + 0];
        float a1 = xe1_t[(k0+k)*XE1_S + e0 + 1];
        float a2 = xe1_t[(k0+k)*XE1_S + e0 + 2];
        float a3 = xe1_t[(k0+k)*XE1_S + e0 + 3];
        float w0 = W_sm[k*WE_S + c0 + 0];
        float w1 = W_sm[k*WE_S + c0 + 1];
        float w2 = W_sm[k*WE_S + c0 + 2];
        float w3 = W_sm[k*WE_S + c0 + 3];
        acc[0][0]+=a0*w0; acc[0][1]+=a0*w1; acc[0][2]+=a0*w2; acc[0][3]+=a0*w3;
        acc[1][0]+=a1*w0; acc[1][1]+=a1*w1; acc[1][2]+=a1*w2; acc[1][3]+=a1*w3;
        acc[2][0]+=a2*w0; acc[2][1]+=a2*w1; acc[2][2]+=a2*w2; acc[2][3]+=a2*w3;
        acc[3][0]+=a3*w0; acc[3][1]+=a3*w1; acc[3][2]+=a3*w2; acc[3][3]+=a3*w3;
      }
    }
    #pragma unroll
    for (int i=0;i<4;i++){
      #pragma unroll
      for (int j=0;j<4;j++)
        xe2_r[(e0+i)*XE2_S + c0 + j] = fsilu(acc[i][j]);
    }
  }
  __syncthreads();

  // ---------------- P3: h = relu(xe2 @ W_g1 + b_g1) -> h_t[q][e] -------
  for (int idx = tid; idx < NBF*32; idx += THREADS) {
    int k = idx >> 5, q = idx & 31;
    W_sm[k*WG1_S + q] = W_g1[idx];
  }
  __syncthreads();
  {
    const int qq = tid & 7;
    const int e  = tid >> 3;      // 0..63
    const int q0 = qq << 2;
    float h0 = b_g1[q0+0], h1 = b_g1[q0+1], h2 = b_g1[q0+2], h3 = b_g1[q0+3];
    for (int k=0;k<NBF;k++){
      float x = xe2_r[e*XE2_S + k];
      h0 += x * W_sm[k*WG1_S + q0+0];
      h1 += x * W_sm[k*WG1_S + q0+1];
      h2 += x * W_sm[k*WG1_S + q0+2];
      h3 += x * W_sm[k*WG1_S + q0+3];
    }
    h_t[(q0+0)*HT_S + e] = fmaxf(h0, 0.0f);
    h_t[(q0+1)*HT_S + e] = fmaxf(h1, 0.0f);
    h_t[(q0+2)*HT_S + e] = fmaxf(h2, 0.0f);
    h_t[(q0+3)*HT_S + e] = fmaxf(h3, 0.0f);
  }
  __syncthreads();

  // ---------------- P4: tensor products (tp_mid 9, tp_all 16) ----------
  {
    const int kk = cq;     // output index: 0..8 -> mid, 9..24 -> all
    const int eg = er;     // 4 edges per thread
    if (kk < 25) {
      float shv[4][16];
      #pragma unroll
      for (int ii=0; ii<4; ii++)
        #pragma unroll
        for (int j=0;j<16;j++)
          shv[ii][j] = sh_s[(eg*4+ii)*SBD + j];
      float accT[4] = {0.f,0.f,0.f,0.f};
      const bool mid = (kk < 9);
      const float* cgbase = mid ? (cg_mid + kk) : (cg_all + (kk-9));
      const int cgstride  = mid ? MBD : SBD;
      for (int i=0;i<SBD;i++){
        float cgv[16];
        #pragma unroll
        for (int j=0;j<16;j++) cgv[j] = cgbase[(i*16+j)*cgstride];
        #pragma unroll
        for (int e=0;e<4;e++){
          float s = 0.0f;
          #pragma unroll
          for (int j=0;j<16;j++) s += shv[e][j]*cgv[j];
          accT[e] += xs_s[(eg*4+e)*SBD + i] * s;
        }
      }
      if (mid) {
        #pragma unroll
        for (int e=0;e<4;e++) tpm_s[(eg*4+e)*MBD + kk] = accT[e];
      } else {
        #pragma unroll
        for (int e=0;e<4;e++) tpa_s[(eg*4+e)*SBD + (kk-9)] = accT[e];
      }
    }
  }
  __syncthreads();
  if (tid < E_TILE) {
    float ta0 = tpa_s[tid*SBD];
    float ssum = 0.0f;
    #pragma unroll
    for (int k=1;k<16;k++) ssum += tpa_s[tid*SBD + k];
    float sg = fsigmoid(ta0);
    sum_s[tid] = ta0*sg + sg*ssum;   // silu(ta0) + sigmoid(ta0)*sum(rest)
  }

  // ---------------- P5: gate = softmax_b(h @ W_g2 + b_g2), keep b=0 ----
  float sden[4][4], z0e[4][4];
  #pragma unroll
  for (int i=0;i<4;i++)
    #pragma unroll
    for (int j=0;j<4;j++){ sden[i][j]=0.0f; z0e[i][j]=0.0f; }
  for (int b=0;b<BRD;b++){
    __syncthreads();   // W_sm safe to overwrite (also publishes sum_s/tpm_s on b==0)
    for (int idx = tid; idx < 32*NBF; idx += THREADS){
      int q = idx >> 7, c = idx & 127;
      W_sm[q*WG2_S + c] = W_g2[q*(BRD*CD) + b*CD + c];
    }
    __syncthreads();
    const float4 bg = *(const float4*)(b_g2 + b*CD + c0);
    float z[4][4];
    #pragma unroll
    for (int i=0;i<4;i++){ z[i][0]=bg.x; z[i][1]=bg.y; z[i][2]=bg.z; z[i][3]=bg.w; }
    for (int q=0;q<32;q++){
      float a0 = h_t[q*HT_S + e0+0];
      float a1 = h_t[q*HT_S + e0+1];
      float a2 = h_t[q*HT_S + e0+2];
      float a3 = h_t[q*HT_S + e0+3];
      float w0 = W_sm[q*WG2_S + c0+0];
      float w1 = W_sm[q*WG2_S + c0+1];
      float w2 = W_sm[q*WG2_S + c0+2];
      float w3 = W_sm[q*WG2_S + c0+3];
      z[0][0]+=a0*w0; z[0][1]+=a0*w1; z[0][2]+=a0*w2; z[0][3]+=a0*w3;
      z[1][0]+=a1*w0; z[1][1]+=a1*w1; z[1][2]+=a1*w2; z[1][3]+=a1*w3;
      z[2][0]+=a2*w0; z[2][1]+=a2*w1; z[2][2]+=a2*w2; z[2][3]+=a2*w3;
      z[3][0]+=a3*w0; z[3][1]+=a3*w1; z[3][2]+=a3*w2; z[3][3]+=a3*w3;
    }
    #pragma unroll
    for (int i=0;i<4;i++)
      #pragma unroll
      for (int j=0;j<4;j++){
        float ez = __expf(z[i][j]);
        sden[i][j] += ez;
        if (b == 0) z0e[i][j] = ez;
      }
  }
  __syncthreads();

  // ---------------- P6: assemble + write out[e][k][c] ------------------
  {
    float wpa[3][4];
    #pragma unroll
    for (int r=0;r<3;r++){
      const float4 w = *(const float4*)(W_path + r*CD + c0);
      wpa[r][0]=w.x; wpa[r][1]=w.y; wpa[r][2]=w.z; wpa[r][3]=w.w;
    }
    #pragma unroll
    for (int i=0;i<4;i++){
      const int e = e0 + i;
      if (e < ne) {
        const int ge = eb + e;
        const float sa = sum_s[e];
        float tpm[9];
        #pragma unroll
        for (int k=0;k<MBD;k++) tpm[k] = tpm_s[e*MBD + k];
        float sg[4], base[4], g4[4], sm0[4];
        #pragma unroll
        for (int j=0;j<4;j++){
          sm0[j]  = tpm[0]*wpa[0][j];
          sg[j]   = fsigmoid(sm0[j]);
          base[j] = xe2_r[e*XE2_S + c0 + j] + sa;
          g4[j]   = z0e[i][j] / sden[i][j];
        }
        float* op = out + (size_t)ge * (MBD*CD) + c0;
        float4 o;
        o.x = sm0[0]*sg[0]*g4[0] + base[0];
        o.y = sm0[1]*sg[1]*g4[1] + base[1];
        o.z = sm0[2]*sg[2]*g4[2] + base[2];
        o.w = sm0[3]*sg[3]*g4[3] + base[3];
        *(float4*)op = o;
        #pragma unroll
        for (int k=1;k<MBD;k++){
          const int r = (k < 4) ? 1 : 2;   // L_OF_K = {0,1,1,1,2,2,2,2,2}
          o.x = tpm[k]*wpa[r][0]*sg[0]*g4[0] + base[0];
          o.y = tpm[k]*wpa[r][1]*sg[1]*g4[1] + base[1];
          o.z = tpm[k]*wpa[r][2]*sg[2]*g4[2] + base[2];
          o.w = tpm[k]*wpa[r][3]*sg[3]*g4[3] + base[3];
          *(float4*)(op + k*CD) = o;
        }
      }
    }
  }
}

extern "C" void kernel_launch(void* const* d_in, const int* in_sizes, int n_in,
                              void* d_out, int out_size, void* d_ws, size_t ws_size,
                              hipStream_t stream) {
  const float* edge_distance  = (const float*)d_in[0];
  const int*   source_element = (const int*)  d_in[1];
  const int*   target_element = (const int*)  d_in[2];
  const float* x_sph   = (const float*)d_in[3];
  const float* edge_sh = (const float*)d_in[4];
  const float* W_dist  = (const float*)d_in[5];
  const float* b_dist  = (const float*)d_in[6];
  const float* src_emb = (const float*)d_in[7];
  const float* tgt_emb = (const float*)d_in[8];
  const float* W_edge  = (const float*)d_in[9];
  const float* b_edge  = (const float*)d_in[10];
  const float* W_g1    = (const float*)d_in[11];
  const float* b_g1    = (const float*)d_in[12];
  const float* W_g2    = (const float*)d_in[13];
  const float* b_g2    = (const float*)d_in[14];
  const float* cg_mid  = (const float*)d_in[15];
  const float* cg_all  = (const float*)d_in[16];
  const float* W_path  = (const float*)d_in[17];
  float* out = (float*)d_out;
  const int E = in_sizes[0];
  const int nblk = (E + E_TILE - 1) / E_TILE;
  hipLaunchKernelGGL(edge_block_kernel, dim3(nblk), dim3(THREADS), 0, stream,
                     edge_distance, source_element, target_element, x_sph, edge_sh,
                     W_dist, b_dist, src_emb, tgt_emb, W_edge, b_edge,
                     W_g1, b_g1, W_g2, b_g2, cg_mid, cg_all, W_path, out, E);
}

// Round 2
// 206.487 us; speedup vs baseline: 2.4536x; 2.4536x over previous
//
#include <hip/hip_runtime.h>
#include <math.h>

typedef unsigned short ushort_t;
typedef unsigned short u16x8 __attribute__((ext_vector_type(8)));
typedef unsigned short u16x4 __attribute__((ext_vector_type(4)));
typedef float f32x4 __attribute__((ext_vector_type(4)));

#define THREADS 512
#define E_TILE  64
#define NBASIS  512
#define NBF     128
#define SBD     16
#define MBD     9
#define NTAP    17
#define XE_S    136   // ushort stride (128 + 8 pad) -> 272B rows, 2-way-free b128 reads
#define H_S     40    // ushort stride (32 + 8 pad)  -> 80B rows

// d_ws layout (ushort bf16)
#define WS_WET   0        // W_edge^T  [n=128][k=128]
#define WS_WG1T  16384    // W_g1^T    [q=32][k=128]
#define WS_WG2T  20480    // W_g2^T    [b*128+n=640][k=32]
#define WS_TOTAL 40960

// LDS offsets (float units)
#define OFF_XS  0      // 64*16
#define OFF_SH  1024   // 64*16
#define OFF_G   2048   // 64*17
#define OFF_JLO 3136   // 64 int
#define OFF_SRC 3200   // 64 int
#define OFF_TGT 3264   // 64 int
#define OFF_TPA 3328   // 64*16
#define OFF_TPM 4352   // 64*10 (stride 10)
#define OFF_SUM 4992   // 64
#define OFF_CGM 5056   // 2304
#define OFF_CGA 7360   // 4096
#define OFF_XE  11456  // 4352 floats = 64*136 ushort (xe1, then xe2)
#define OFF_H   15808  // 1280 floats = 64*40 ushort
#define SMEM_FLOATS 17088   // 68.3 KB -> 2 blocks/CU

__device__ __forceinline__ float fsigmoid(float x){ return 1.0f/(1.0f + __expf(-x)); }
__device__ __forceinline__ float fsilu(float x){ return x/(1.0f + __expf(-x)); }

__device__ __forceinline__ ushort_t f2bf(float f){
  unsigned int u = __float_as_uint(f);
  u += 0x7FFFu + ((u >> 16) & 1u);
  return (ushort_t)(u >> 16);
}
__device__ __forceinline__ float bf2f(ushort_t h){
  return __uint_as_float(((unsigned int)h) << 16);
}
__device__ __forceinline__ void mfma_bf16(f32x4& d, u16x8 a, u16x8 b){
  // D[m][n] += A[m][k] * B[k][n]; a: lane(l) = A[l&15][(l>>4)*8+j], b: lane(l) = B[(l>>4)*8+j][l&15]
  asm volatile("v_mfma_f32_16x16x32_bf16 %0, %1, %2, %0" : "+v"(d) : "v"(a), "v"(b));
}

__global__ void prep_weights_kernel(const float* __restrict__ We,
                                    const float* __restrict__ Wg1,
                                    const float* __restrict__ Wg2,
                                    ushort_t* __restrict__ ws){
  int tid = blockIdx.x * 256 + threadIdx.x;
  if (tid < 16384) {                       // WeT[n][k] = We[k][n]
    int n = tid >> 7, k = tid & 127;
    ws[WS_WET + tid] = f2bf(We[k*128 + n]);
  } else if (tid < 20480) {                // Wg1T[q][k] = Wg1[k][q]
    int r = tid - 16384; int q = r >> 7, k = r & 127;
    ws[tid] = f2bf(Wg1[k*32 + q]);
  } else if (tid < WS_TOTAL) {             // Wg2T[b*128+n][k] = Wg2[k][b*128+n]
    int r = tid - 20480; int bn = r >> 5, k = r & 31;
    ws[tid] = f2bf(Wg2[k*640 + bn]);
  }
}

__global__ __launch_bounds__(THREADS, 4)
void edge_block_kernel(
    const float* __restrict__ edge_distance,
    const int*   __restrict__ source_element,
    const int*   __restrict__ target_element,
    const float* __restrict__ x_sph,
    const float* __restrict__ edge_sh,
    const float* __restrict__ W_dist,
    const float* __restrict__ b_dist,
    const float* __restrict__ src_emb,
    const float* __restrict__ tgt_emb,
    const float* __restrict__ b_edge,
    const float* __restrict__ b_g1,
    const float* __restrict__ b_g2,
    const float* __restrict__ cg_mid,
    const float* __restrict__ cg_all,
    const float* __restrict__ W_path,
    const ushort_t* __restrict__ wT,
    float* __restrict__ out,
    int E)
{
  __shared__ float smem[SMEM_FLOATS];
  float* xs_s  = smem + OFF_XS;
  float* sh_s  = smem + OFF_SH;
  float* g_s   = smem + OFF_G;
  int*   jlo_s = (int*)(smem + OFF_JLO);
  int*   src_s = (int*)(smem + OFF_SRC);
  int*   tgt_s = (int*)(smem + OFF_TGT);
  float* tpa_s = smem + OFF_TPA;
  float* tpm_s = smem + OFF_TPM;
  float* sum_s = smem + OFF_SUM;
  float* cgm_s = smem + OFF_CGM;
  float* cga_s = smem + OFF_CGA;
  ushort_t* xe = (ushort_t*)(smem + OFF_XE);
  ushort_t* hS = (ushort_t*)(smem + OFF_H);

  const int tid  = threadIdx.x;
  const int lane = tid & 63;
  const int wid  = tid >> 6;       // 0..7
  const int l16  = lane & 15;
  const int lq   = lane >> 4;      // 0..3
  const int eb   = blockIdx.x * E_TILE;
  const int ne   = min(E_TILE, E - eb);

  // ---------------- P0: stage inputs ----------------
  for (int idx = tid; idx < E_TILE*SBD; idx += THREADS) {
    int e = idx >> 4;
    bool v = (e < ne);
    int gidx = (eb + e)*SBD + (idx & 15);
    xs_s[idx] = v ? x_sph[gidx]   : 0.0f;
    sh_s[idx] = v ? edge_sh[gidx] : 0.0f;
  }
  for (int idx = tid; idx < SBD*SBD*MBD; idx += THREADS) cgm_s[idx] = cg_mid[idx];
  for (int idx = tid; idx < SBD*SBD*SBD; idx += THREADS) cga_s[idx] = cg_all[idx];
  if (tid < E_TILE) {
    bool v = (tid < ne);
    int ge = eb + tid;
    src_s[tid] = v ? source_element[ge] : 0;
    tgt_s[tid] = v ? target_element[ge] : 0;
  }
  const float INVD = (float)(NBASIS - 1) / 6.0f;   // 511/6
  for (int idx = tid; idx < E_TILE*NTAP; idx += THREADS) {
    int e = idx / NTAP;
    int t = idx - e*NTAP;
    bool v = (e < ne);
    float d  = v ? edge_distance[eb + e] : 0.0f;
    float jd = d * INVD;
    int jlo  = (int)floorf(jd) - 8;
    int j    = jlo + t;
    float dj = jd - (float)j;
    float g  = (v && j >= 0 && j < NBASIS) ? __expf(-0.5f*dj*dj) : 0.0f;
    g_s[e*NTAP + t] = g;
    if (t == 0) jlo_s[e] = jlo;
  }
  __syncthreads();

  // ---------------- P1: x_dist (17 taps) + emb + silu -> xe1 bf16 ------
  {
    const int er = tid >> 5;       // 0..15 -> 4 edges each
    const int cq = tid & 31;       // 0..31 -> 4 channels each
    const int e0 = er << 2;
    const int c0 = cq << 2;
    float acc[4][4];
    const float4 bd = *(const float4*)(b_dist + c0);
    #pragma unroll
    for (int i=0;i<4;i++){ acc[i][0]=bd.x; acc[i][1]=bd.y; acc[i][2]=bd.z; acc[i][3]=bd.w; }
    for (int t=0; t<NTAP; t++){
      #pragma unroll
      for (int i=0;i<4;i++){
        int e = e0 + i;
        float g = g_s[e*NTAP + t];
        int j = jlo_s[e] + t;
        j = max(0, min(NBASIS-1, j));
        const float4 w = *(const float4*)(W_dist + j*NBF + c0);
        acc[i][0] += g*w.x; acc[i][1] += g*w.y; acc[i][2] += g*w.z; acc[i][3] += g*w.w;
      }
    }
    #pragma unroll
    for (int i=0;i<4;i++){
      int e = e0 + i;
      const float4 se = *(const float4*)(src_emb + src_s[e]*NBF + c0);
      const float4 te = *(const float4*)(tgt_emb + tgt_s[e]*NBF + c0);
      u16x4 v;
      v[0] = f2bf(fsilu(acc[i][0] + se.x + te.x));
      v[1] = f2bf(fsilu(acc[i][1] + se.y + te.y));
      v[2] = f2bf(fsilu(acc[i][2] + se.z + te.z));
      v[3] = f2bf(fsilu(acc[i][3] + se.w + te.w));
      *(u16x4*)(xe + e*XE_S + c0) = v;
    }
  }

  // ---------------- P4: tensor products (VALU, cg from LDS) ------------
  {
    const int kk = tid & 31;       // output idx: 0..8 mid, 9..24 all
    const int eg = tid >> 5;       // 4 edges
    if (kk < 25) {
      float shv[4][16];
      #pragma unroll
      for (int ii=0; ii<4; ii++)
        #pragma unroll
        for (int j=0;j<16;j++)
          shv[ii][j] = sh_s[(eg*4+ii)*SBD + j];
      float accT[4] = {0.f,0.f,0.f,0.f};
      const bool mid = (kk < 9);
      const float* cgb = mid ? (cgm_s + kk) : (cga_s + (kk-9));
      const int cgs = mid ? MBD : SBD;
      for (int i=0;i<SBD;i++){
        float cgv[16];
        #pragma unroll
        for (int j=0;j<16;j++) cgv[j] = cgb[(i*16+j)*cgs];
        #pragma unroll
        for (int e=0;e<4;e++){
          float s = 0.0f;
          #pragma unroll
          for (int j=0;j<16;j++) s += shv[e][j]*cgv[j];
          accT[e] += xs_s[(eg*4+e)*SBD + i] * s;
        }
      }
      if (mid) {
        #pragma unroll
        for (int e=0;e<4;e++) tpm_s[(eg*4+e)*10 + kk] = accT[e];
      } else {
        #pragma unroll
        for (int e=0;e<4;e++) tpa_s[(eg*4+e)*SBD + (kk-9)] = accT[e];
      }
    }
  }
  __syncthreads();   // publishes xe1, tpa, tpm

  // ---------------- P2: xe2 = silu(xe1 @ W_edge + b_edge) via MFMA -----
  const int m0 = (wid & 3) * 16;
  const int nb = (wid >> 2) * 64;
  {
    f32x4 acc2[4];
    #pragma unroll
    for (int t=0;t<4;t++) acc2[t] = (f32x4){0.f,0.f,0.f,0.f};
    #pragma unroll
    for (int kk=0; kk<4; kk++){
      const u16x8 a = *(const u16x8*)(xe + (m0 + l16)*XE_S + kk*32 + lq*8);
      #pragma unroll
      for (int t=0;t<4;t++){
        const u16x8 b = *(const u16x8*)(wT + WS_WET + (nb + t*16 + l16)*128 + kk*32 + lq*8);
        mfma_bf16(acc2[t], a, b);
      }
    }
    __syncthreads();   // all xe1 reads done -> safe to overwrite with xe2
    #pragma unroll
    for (int t=0;t<4;t++){
      const int n = nb + t*16 + l16;
      const float be = b_edge[n];
      #pragma unroll
      for (int j=0;j<4;j++){
        const int m = m0 + lq*4 + j;
        xe[m*XE_S + n] = f2bf(fsilu(acc2[t][j] + be));
      }
    }
  }
  if (tid < E_TILE) {   // tp_all_g row-sum (tpa published 2 barriers ago)
    float ta0 = tpa_s[tid*SBD];
    float ss = 0.0f;
    #pragma unroll
    for (int k=1;k<16;k++) ss += tpa_s[tid*SBD + k];
    float sg = fsigmoid(ta0);
    sum_s[tid] = ta0*sg + sg*ss;
  }
  __syncthreads();   // publishes xe2, sum_s

  // ---------------- P3: h = relu(xe2 @ W_g1 + b_g1) via MFMA -----------
  {
    const int n0 = (wid >> 2) * 16;   // 0 or 16
    f32x4 acc3 = (f32x4){0.f,0.f,0.f,0.f};
    #pragma unroll
    for (int kk=0; kk<4; kk++){
      const u16x8 a = *(const u16x8*)(xe + (m0 + l16)*XE_S + kk*32 + lq*8);
      const u16x8 b = *(const u16x8*)(wT + WS_WG1T + (n0 + l16)*128 + kk*32 + lq*8);
      mfma_bf16(acc3, a, b);
    }
    const float bg = b_g1[n0 + l16];
    #pragma unroll
    for (int j=0;j<4;j++){
      const int m = m0 + lq*4 + j;
      hS[m*H_S + n0 + l16] = f2bf(fmaxf(acc3[j] + bg, 0.0f));
    }
  }
  __syncthreads();   // publishes h

  // ---------------- P5: gate branch-0 via MFMA + in-reg softmax --------
  const int cb = (wid >> 2) * 64;
  float sden[4][4], z0e[4][4];
  #pragma unroll
  for (int t=0;t<4;t++)
    #pragma unroll
    for (int j=0;j<4;j++){ sden[t][j]=0.0f; z0e[t][j]=0.0f; }
  {
    const u16x8 ah = *(const u16x8*)(hS + (m0 + l16)*H_S + lq*8);
    #pragma unroll
    for (int b=0;b<5;b++){
      #pragma unroll
      for (int t=0;t<4;t++){
        const u16x8 bw = *(const u16x8*)(wT + WS_WG2T + (b*128 + cb + t*16 + l16)*32 + lq*8);
        f32x4 z = (f32x4){0.f,0.f,0.f,0.f};
        mfma_bf16(z, ah, bw);
        const float bg = b_g2[b*128 + cb + t*16 + l16];
        #pragma unroll
        for (int j=0;j<4;j++){
          float ez = __expf(z[j] + bg);
          sden[t][j] += ez;
          if (b == 0) z0e[t][j] = ez;
        }
      }
    }
  }

  // ---------------- P6: assemble + write out[e][k][c] ------------------
  {
    float wp[4][3];
    #pragma unroll
    for (int t=0;t<4;t++){
      const int c = cb + t*16 + l16;
      wp[t][0] = W_path[c];
      wp[t][1] = W_path[128 + c];
      wp[t][2] = W_path[256 + c];
    }
    #pragma unroll
    for (int j=0;j<4;j++){
      const int m = m0 + lq*4 + j;
      if (m < ne) {
        const float sa = sum_s[m];
        float tpmv[9];
        #pragma unroll
        for (int k=0;k<MBD;k++) tpmv[k] = tpm_s[m*10 + k];
        float* op = out + (size_t)(eb + m) * (MBD*NBF);
        #pragma unroll
        for (int t=0;t<4;t++){
          const int c = cb + t*16 + l16;
          const float g0 = z0e[t][j] / sden[t][j];
          const float base = bf2f(xe[m*XE_S + c]) + sa;
          const float s0 = tpmv[0] * wp[t][0];
          const float sg = fsigmoid(s0);
          const float gg = sg * g0;
          op[c] = s0*gg + base;
          #pragma unroll
          for (int k=1;k<MBD;k++){
            const float w = (k < 4) ? wp[t][1] : wp[t][2];
            op[k*NBF + c] = tpmv[k]*w*gg + base;
          }
        }
      }
    }
  }
}

extern "C" void kernel_launch(void* const* d_in, const int* in_sizes, int n_in,
                              void* d_out, int out_size, void* d_ws, size_t ws_size,
                              hipStream_t stream) {
  const float* edge_distance  = (const float*)d_in[0];
  const int*   source_element = (const int*)  d_in[1];
  const int*   target_element = (const int*)  d_in[2];
  const float* x_sph   = (const float*)d_in[3];
  const float* edge_sh = (const float*)d_in[4];
  const float* W_dist  = (const float*)d_in[5];
  const float* b_dist  = (const float*)d_in[6];
  const float* src_emb = (const float*)d_in[7];
  const float* tgt_emb = (const float*)d_in[8];
  const float* W_edge  = (const float*)d_in[9];
  const float* b_edge  = (const float*)d_in[10];
  const float* W_g1    = (const float*)d_in[11];
  const float* b_g1    = (const float*)d_in[12];
  const float* W_g2    = (const float*)d_in[13];
  const float* b_g2    = (const float*)d_in[14];
  const float* cg_mid  = (const float*)d_in[15];
  const float* cg_all  = (const float*)d_in[16];
  const float* W_path  = (const float*)d_in[17];
  float* out = (float*)d_out;
  ushort_t* ws = (ushort_t*)d_ws;
  const int E = in_sizes[0];

  hipLaunchKernelGGL(prep_weights_kernel, dim3((WS_TOTAL + 255)/256), dim3(256), 0, stream,
                     W_edge, W_g1, W_g2, ws);

  const int nblk = (E + E_TILE - 1) / E_TILE;
  hipLaunchKernelGGL(edge_block_kernel, dim3(nblk), dim3(THREADS), 0, stream,
                     edge_distance, source_element, target_element, x_sph, edge_sh,
                     W_dist, b_dist, src_emb, tgt_emb, b_edge,
                     b_g1, b_g2, cg_mid, cg_all, W_path, ws, out, E);
}